// Round 1
// baseline (669.876 us; speedup 1.0000x reference)
//
#include <hip/hip_runtime.h>

// Problem constants (fixed by setup_inputs)
constexpr int B  = 8;
constexpr int LQ = 2048;
constexpr int LK = 4096;
constexpr int C  = 1024;
constexpr int H  = 16;
constexpr int D  = 64;     // head dim
constexpr int CS = 8;      // code size
constexpr int KC = 256;    // 2^CS buckets
constexpr float SCALE = 0.125f; // d^-0.5 = 1/8

// ---------------------------------------------------------------------------
// Kernel 1: per-kv-token bucket index + per-(batch,bucket) counts.
// code_j = k_row . Wc_j + bc_j ; normalization never flips sign -> skip it.
// bit_j = (code_j >= 0), idx = sum bit_j << (7-j)
// One wave per row; Wc (8x1024 = 32 KB) staged in LDS.
// ---------------------------------------------------------------------------
__global__ __launch_bounds__(256) void k_codes(
    const float* __restrict__ kmat, const float* __restrict__ Wc,
    const float* __restrict__ bc, int* __restrict__ idx,
    float* __restrict__ counts)
{
  __shared__ float wS[CS * C]; // 32 KB
  const int tid = threadIdx.x;

  // stage Wc (2048 float4)
  {
    const float4* wsrc = (const float4*)Wc;
    float4* wdst = (float4*)wS;
#pragma unroll
    for (int i = 0; i < 8; ++i) wdst[tid + i * 256] = wsrc[tid + i * 256];
  }
  __syncthreads();

  const int wave = tid >> 6, lane = tid & 63;
  const int r = blockIdx.x * 4 + wave;        // kv row, < B*LK
  const float4* krow = (const float4*)(kmat + (size_t)r * C);

  float acc[CS];
#pragma unroll
  for (int j = 0; j < CS; ++j) acc[j] = 0.f;

#pragma unroll
  for (int rep = 0; rep < 4; ++rep) {
    float4 kv = krow[rep * 64 + lane];        // coalesced 16B/lane
    const int dbase = (rep * 64 + lane) * 4;
#pragma unroll
    for (int j = 0; j < CS; ++j) {
      float4 wv = *(const float4*)&wS[j * C + dbase];
      acc[j] += kv.x * wv.x + kv.y * wv.y + kv.z * wv.z + kv.w * wv.w;
    }
  }
  // wave-wide reduction (64 lanes)
#pragma unroll
  for (int j = 0; j < CS; ++j) {
#pragma unroll
    for (int off = 32; off >= 1; off >>= 1)
      acc[j] += __shfl_xor(acc[j], off, 64);
  }
  if (lane == 0) {
    int ix = 0;
#pragma unroll
    for (int j = 0; j < CS; ++j) {
      float cj = acc[j] + bc[j];
      ix |= (cj >= 0.f ? 1 : 0) << (7 - j);
    }
    idx[r] = ix;
    const int b = r >> 12; // r / LK (LK = 4096)
    atomicAdd(&counts[b * KC + ix], 1.0f);
  }
}

// ---------------------------------------------------------------------------
// Kernel 2: scatter-add v rows into cod_v[b][idx][:].
// Block = (32-column chunk, batch). LDS bucket array [256][33] (pad breaks
// power-of-2 bank aliasing), plus staged idx slice. Each block owns its
// (b, col-chunk) output region -> plain stores, no global atomics, no zeroing.
// ---------------------------------------------------------------------------
__global__ __launch_bounds__(256) void k_scatter(
    const float* __restrict__ v, const int* __restrict__ idx,
    float* __restrict__ cod_v)
{
  __shared__ float buck[KC * 33];  // 33.8 KB
  __shared__ int   idxS[LK];       // 16 KB
  const int tid = threadIdx.x;
  const int c0 = blockIdx.x * 32;  // column chunk
  const int b  = blockIdx.y;

  for (int i = tid; i < KC * 33; i += 256) buck[i] = 0.f;
  {
    const int4* src = (const int4*)(idx + (size_t)b * LK);
    int4* dst = (int4*)idxS;
    for (int i = tid; i < LK / 4; i += 256) dst[i] = src[i];
  }
  __syncthreads();

  const int rsub = tid >> 3;   // 0..31 (32 rows per pass)
  const int cg   = tid & 7;    // 0..7  (8 float4 = 32 cols)
#pragma unroll 4
  for (int it = 0; it < LK / 32; ++it) {
    const int row = it * 32 + rsub;
    const int ix  = idxS[row];
    float4 vv = *(const float4*)(v + (size_t)(b * LK + row) * C + c0 + cg * 4);
    float* base = &buck[ix * 33 + cg * 4];
    atomicAdd(base + 0, vv.x);
    atomicAdd(base + 1, vv.y);
    atomicAdd(base + 2, vv.z);
    atomicAdd(base + 3, vv.w);
  }
  __syncthreads();

  // write out bucket sums
  const int c = tid & 31, kgrp = tid >> 5;
  for (int kk = 0; kk < 32; ++kk) {
    const int kb = kgrp * 32 + kk;
    cod_v[(size_t)(b * KC + kb) * C + c0 + c] = buck[kb * 33 + c];
  }
}

// ---------------------------------------------------------------------------
// Kernel 3: attention. Block = (64 q-rows, head h, batch b), 256 threads.
// Scores factorized through codebook: s_k = sum_j bit_j(k)? t_j : t_{j+8},
// t_j = scale * q_h . codebook_j[h-slice]. p_k = (count_k>0) * exp(s_k).
// out = (sum p_k cod_v_k) / (sum p_k counts_k)  -- softmax normalizer cancels,
// |s| << 88 so no max subtraction needed.
// Phase 2 is a register-tiled 4x4 GEMM over 64-bucket chunks from LDS.
// ---------------------------------------------------------------------------
__global__ __launch_bounds__(256) void k_attn(
    const float* __restrict__ q, const float* __restrict__ codebook,
    const float* __restrict__ cod_v, const float* __restrict__ counts,
    float* __restrict__ out)
{
  __shared__ float Qs[64 * 65];    // q tile (scaled), stride 65
  __shared__ float cbS[16 * 65];   // codebook h-slice
  __shared__ float tS[64 * 17];    // t[m][j], stride 17
  __shared__ float PtS[64 * 68];   // P^T chunk: [k-local][m]
  __shared__ float VcS[64 * 68];   // V chunk:   [k-local][d]
  __shared__ float cntS[KC];
  __shared__ float denS[64];
  // total 61.2 KB -> 2 blocks/CU

  const int tid = threadIdx.x;
  const int qt = blockIdx.x, h = blockIdx.y, b = blockIdx.z;
  const size_t qrow0 = (size_t)b * LQ + qt * 64;

  // ---- stage Qs (scaled), cbS, cntS ----
  {
    const int m = tid >> 2, part = tid & 3;
    const float* src = q + (qrow0 + m) * C + h * D;
#pragma unroll
    for (int i = 0; i < 4; ++i) {
      const int dd = part * 16 + i * 4;
      float4 f = *(const float4*)(src + dd);
      float* dst = &Qs[m * 65 + dd];
      dst[0] = f.x * SCALE; dst[1] = f.y * SCALE;
      dst[2] = f.z * SCALE; dst[3] = f.w * SCALE;
    }
  }
  {
    const int j = tid >> 4, d4 = (tid & 15) * 4;
    float4 f = *(const float4*)(codebook + (size_t)j * C + h * D + d4);
    float* dst = &cbS[j * 65 + d4];
    dst[0] = f.x; dst[1] = f.y; dst[2] = f.z; dst[3] = f.w;
  }
  cntS[tid] = counts[b * KC + tid];
  __syncthreads();

  // ---- phase T: t[m][j] = Qs[m][:] . cbS[j][:] ----
  {
    const int m = tid >> 2, jg = tid & 3;
    float t0 = 0.f, t1 = 0.f, t2 = 0.f, t3 = 0.f;
    const float* qm  = &Qs[m * 65];
    const float* c0p = &cbS[(jg * 4 + 0) * 65];
    const float* c1p = &cbS[(jg * 4 + 1) * 65];
    const float* c2p = &cbS[(jg * 4 + 2) * 65];
    const float* c3p = &cbS[(jg * 4 + 3) * 65];
#pragma unroll 16
    for (int dd = 0; dd < 64; ++dd) {
      const float qv = qm[dd];
      t0 += qv * c0p[dd]; t1 += qv * c1p[dd];
      t2 += qv * c2p[dd]; t3 += qv * c3p[dd];
    }
    float* td = &tS[m * 17 + jg * 4];
    td[0] = t0; td[1] = t1; td[2] = t2; td[3] = t3;
  }
  __syncthreads();

  // thread tiling for phase B: 4 m-rows x 4 d-cols per thread
  const int ni = tid & 15, mi = (tid >> 4) & 3, wq = tid >> 6;
  const int m0 = wq * 16 + mi * 4, n0 = ni * 4;
  float accv[4][4];
  float accd[4] = {0.f, 0.f, 0.f, 0.f};
#pragma unroll
  for (int i = 0; i < 4; ++i)
#pragma unroll
    for (int jj = 0; jj < 4; ++jj) accv[i][jj] = 0.f;

  // phase-A mapping: thread (m, hi) computes p for 16 buckets
  const int ma = tid & 63, hi = tid >> 6;
  float tr[16];
#pragma unroll
  for (int j = 0; j < 16; ++j) tr[j] = tS[ma * 17 + j];

  for (int kc = 0; kc < KC; kc += 64) {
    // stage V chunk (cod_v[b][kc..kc+64)[h-slice])
    {
      const int kl = tid >> 2, p4 = tid & 3;
      const float* src = cod_v + (size_t)(b * KC + kc + kl) * C + h * D;
#pragma unroll
      for (int i = 0; i < 4; ++i) {
        const int dd = p4 * 16 + i * 4;
        *(float4*)&VcS[kl * 68 + dd] = *(const float4*)(src + dd);
      }
    }
    // phase A: p values for this chunk -> PtS[k-local][m]
#pragma unroll
    for (int lo = 0; lo < 16; ++lo) {
      const int kk = kc + hi * 16 + lo;
      float s = 0.f;
#pragma unroll
      for (int j = 0; j < 8; ++j)
        s += ((kk >> (7 - j)) & 1) ? tr[j] : tr[j + 8];
      const float p = (cntS[kk] > 0.f) ? __expf(s) : 0.f;
      PtS[(hi * 16 + lo) * 68 + ma] = p;
    }
    __syncthreads();

    // phase B: accumulate num (and den on ni==0 lanes)
#pragma unroll 8
    for (int kl = 0; kl < 64; ++kl) {
      float4 pv = *(const float4*)&PtS[kl * 68 + m0]; // 4-addr broadcast
      float4 vv = *(const float4*)&VcS[kl * 68 + n0]; // conflict-free
      const float pm[4] = {pv.x, pv.y, pv.z, pv.w};
      const float vn[4] = {vv.x, vv.y, vv.z, vv.w};
#pragma unroll
      for (int i = 0; i < 4; ++i)
#pragma unroll
        for (int jj = 0; jj < 4; ++jj) accv[i][jj] += pm[i] * vn[jj];
      if (ni == 0) {
        const float cv = cntS[kc + kl];
#pragma unroll
        for (int i = 0; i < 4; ++i) accd[i] += pm[i] * cv;
      }
    }
    __syncthreads();
  }

  // ---- epilogue ----
  if (ni == 0) {
#pragma unroll
    for (int i = 0; i < 4; ++i) denS[m0 + i] = accd[i];
  }
  __syncthreads();
#pragma unroll
  for (int i = 0; i < 4; ++i) {
    const float inv = 1.0f / denS[m0 + i];
    float4 o;
    o.x = accv[i][0] * inv; o.y = accv[i][1] * inv;
    o.z = accv[i][2] * inv; o.w = accv[i][3] * inv;
    *(float4*)(out + (qrow0 + m0 + i) * C + h * D + n0) = o;
  }
}

// ---------------------------------------------------------------------------
extern "C" void kernel_launch(void* const* d_in, const int* in_sizes, int n_in,
                              void* d_out, int out_size, void* d_ws, size_t ws_size,
                              hipStream_t stream) {
  (void)in_sizes; (void)n_in; (void)out_size; (void)ws_size;
  const float* q  = (const float*)d_in[0];
  const float* k  = (const float*)d_in[1];
  const float* v  = (const float*)d_in[2];
  const float* Wc = (const float*)d_in[3];
  const float* bc = (const float*)d_in[4];
  const float* cb = (const float*)d_in[5];
  float* out = (float*)d_out;

  char* ws = (char*)d_ws;
  int*   idxp  = (int*)ws;                   // 32768 ints  (128 KB)
  float* cntp  = (float*)(ws + 0x20000);     // 2048 floats (8 KB)
  float* codvp = (float*)(ws + 0x28000);     // 8*256*1024 floats (8 MB)

  hipMemsetAsync(cntp, 0, B * KC * sizeof(float), stream);
  hipLaunchKernelGGL(k_codes,   dim3(B * LK / 4), dim3(256), 0, stream,
                     k, Wc, bc, idxp, cntp);
  hipLaunchKernelGGL(k_scatter, dim3(C / 32, B),  dim3(256), 0, stream,
                     v, idxp, codvp);
  hipLaunchKernelGGL(k_attn,    dim3(LQ / 64, H, B), dim3(256), 0, stream,
                     q, cb, codvp, cntp, out);
}

// Round 2
// 511.963 us; speedup vs baseline: 1.3084x; 1.3084x over previous
//
#include <hip/hip_runtime.h>
#include <hip/hip_bf16.h>

constexpr int B  = 8;
constexpr int LQ = 2048;
constexpr int LK = 4096;
constexpr int C  = 1024;
constexpr int H  = 16;
constexpr int D  = 64;
constexpr int CS = 8;
constexpr int KC = 256;
constexpr float SCALE = 0.125f;

typedef __attribute__((ext_vector_type(8))) short short8;
typedef __attribute__((ext_vector_type(4))) float f32x4;

union FragU { unsigned u[4]; short8 s; float4 f; };

__device__ inline unsigned bfp(float a, float b) {
  __hip_bfloat16 x = __float2bfloat16(a), y = __float2bfloat16(b);
  unsigned short ux = *reinterpret_cast<unsigned short*>(&x);
  unsigned short uy = *reinterpret_cast<unsigned short*>(&y);
  return (unsigned)ux | ((unsigned)uy << 16);
}

// ---------------------------------------------------------------------------
// Kernel 1: bucket index per kv token + per-(batch,bucket) counts.
// 32 rows per block (8 per wave) to amortize the 32 KB Wc LDS stage.
// ---------------------------------------------------------------------------
__global__ __launch_bounds__(256) void k_codes(
    const float* __restrict__ kmat, const float* __restrict__ Wc,
    const float* __restrict__ bc, int* __restrict__ idx,
    float* __restrict__ counts)
{
  __shared__ float wS[CS * C]; // 32 KB
  const int tid = threadIdx.x;
  {
    const float4* wsrc = (const float4*)Wc;
    float4* wdst = (float4*)wS;
#pragma unroll
    for (int i = 0; i < 8; ++i) wdst[tid + i * 256] = wsrc[tid + i * 256];
  }
  __syncthreads();

  const int wave = tid >> 6, lane = tid & 63;

  for (int i = 0; i < 8; ++i) {
    const int r = blockIdx.x * 32 + wave * 8 + i;
    const float4* krow = (const float4*)(kmat + (size_t)r * C);
    float acc[CS];
#pragma unroll
    for (int j = 0; j < CS; ++j) acc[j] = 0.f;
#pragma unroll
    for (int rep = 0; rep < 4; ++rep) {
      float4 kv = krow[rep * 64 + lane];
      const int dbase = (rep * 64 + lane) * 4;
#pragma unroll
      for (int j = 0; j < CS; ++j) {
        float4 wv = *(const float4*)&wS[j * C + dbase];
        acc[j] += kv.x * wv.x + kv.y * wv.y + kv.z * wv.z + kv.w * wv.w;
      }
    }
#pragma unroll
    for (int j = 0; j < CS; ++j) {
#pragma unroll
      for (int off = 32; off >= 1; off >>= 1)
        acc[j] += __shfl_xor(acc[j], off, 64);
    }
    if (lane == 0) {
      int ix = 0;
#pragma unroll
      for (int j = 0; j < CS; ++j) {
        float cj = acc[j] + bc[j];
        ix |= (cj >= 0.f ? 1 : 0) << (7 - j);
      }
      idx[r] = ix;
      const int bb = r >> 12; // r / LK
      atomicAdd(&counts[bb * KC + ix], 1.0f);
    }
  }
}

// ---------------------------------------------------------------------------
// Kernel 2: scatter-add v rows into per-part buckets. Grid (C/32, B, R);
// each block owns (col-chunk, b, row-slice) -> LDS accumulate, plain stores.
// ---------------------------------------------------------------------------
__global__ __launch_bounds__(256) void k_scatter(
    const float* __restrict__ v, const int* __restrict__ idx,
    float* __restrict__ dst, int rows_per)
{
  __shared__ float buck[KC * 33]; // 33.8 KB
  const int tid = threadIdx.x;
  const int c0 = blockIdx.x * 32, b = blockIdx.y, z = blockIdx.z;
  float* part = dst + (size_t)z * B * KC * C;

  for (int i = tid; i < KC * 33; i += 256) buck[i] = 0.f;
  __syncthreads();

  const int rsub = tid >> 3, cg = tid & 7;
  const int r0 = z * rows_per;
  const int iters = rows_per / 32;
#pragma unroll 8
  for (int it = 0; it < iters; ++it) {
    const int row = r0 + it * 32 + rsub;
    const int ix = idx[b * LK + row];
    float4 vv = *(const float4*)(v + (size_t)(b * LK + row) * C + c0 + cg * 4);
    float* base = &buck[ix * 33 + cg * 4];
    atomicAdd(base + 0, vv.x);
    atomicAdd(base + 1, vv.y);
    atomicAdd(base + 2, vv.z);
    atomicAdd(base + 3, vv.w);
  }
  __syncthreads();

  const int c = tid & 31, kg = tid >> 5;
  for (int kk = 0; kk < 32; ++kk) {
    const int kb = kg * 32 + kk;
    part[(size_t)(b * KC + kb) * C + c0 + c] = buck[kb * 33 + c];
  }
}

// ---------------------------------------------------------------------------
// Kernel 2b: merge 4 partial cod_v arrays.
// ---------------------------------------------------------------------------
__global__ __launch_bounds__(256) void k_merge(
    const float4* __restrict__ p, float4* __restrict__ o)
{
  const size_t n = (size_t)B * KC * C / 4;
  const size_t i = (size_t)blockIdx.x * 256 + threadIdx.x;
  float4 a = p[i], b2 = p[i + n], c2 = p[i + 2 * n], d2 = p[i + 3 * n];
  float4 r;
  r.x = a.x + b2.x + c2.x + d2.x;
  r.y = a.y + b2.y + c2.y + d2.y;
  r.z = a.z + b2.z + c2.z + d2.z;
  r.w = a.w + b2.w + c2.w + d2.w;
  o[i] = r;
}

// ---------------------------------------------------------------------------
// Kernel 3: attention via bf16 MFMA. Block = 128 q-rows x head x batch.
//  t[m][j] = (scale*q[m]) . cb[j]  (4 MFMAs/wave, C-layout -> LDS transpose)
//  p[m][k] = exp( sum_j bit_j(k) ? t_j : t_{j+8} )   (no mask needed: empty
//            buckets have v=0 and count=0, contribute 0 to num and den)
//  num/den via P[128x256] x V[256x80] MFMA; V col 64 = counts, 65..79 = 0.
// ---------------------------------------------------------------------------
__global__ __launch_bounds__(256) void k_attn(
    const float* __restrict__ q, const float* __restrict__ cb,
    const float* __restrict__ cod_v, const float* __restrict__ counts,
    float* __restrict__ out)
{
  __shared__ __align__(16) char smem[59392];
  float4* VF = (float4*)smem;             // 2560 f4 : V B-frags (40960 B)
  float4* QA = (float4*)(smem + 40960);   // 1024 f4 : Q A-frags (16384 B)
  float4* CBf = (float4*)(smem + 57344);  // 128 f4  : cb B-frags (2048 B)
  float*  TS = (float*)(smem + 40960);    // alias over QA after barrier 2

  const int tid = threadIdx.x;
  const int lane = tid & 63, wq = tid >> 6, quad = lane >> 4;
  const int h = blockIdx.y, b = blockIdx.z;
  const int q0 = blockIdx.x * 128;

  // ---- stage V frags (bf16, B-operand layout) ----
#pragma unroll
  for (int it = 0; it < 8; ++it) {
    const int o = it * 4 + (tid >> 6);   // k-octet 0..31
    const int n = tid & 63;              // column 0..63
    const float* src = cod_v + (size_t)(b * KC + o * 8) * C + h * D + n;
    float f[8];
#pragma unroll
    for (int r = 0; r < 8; ++r) f[r] = src[(size_t)r * C];
    FragU u;
    u.u[0] = bfp(f[0], f[1]); u.u[1] = bfp(f[2], f[3]);
    u.u[2] = bfp(f[4], f[5]); u.u[3] = bfp(f[6], f[7]);
    VF[((o >> 2) * 5 + (n >> 4)) * 64 + (o & 3) * 16 + (n & 15)] = u.f;
  }
  // counts n-tile (t=4): zero non-count slots, write counts at nl==0
  {
    float4 z4 = make_float4(0.f, 0.f, 0.f, 0.f);
    for (int i = tid; i < 512; i += 256) {
      const int qc = i >> 6, l = i & 63;
      if ((l & 15) != 0) VF[(qc * 5 + 4) * 64 + l] = z4;
    }
    if (tid < 32) {
      const int o = tid;
      const float* cs = counts + b * KC + o * 8;
      float f[8];
#pragma unroll
      for (int r = 0; r < 8; ++r) f[r] = cs[r];
      FragU u;
      u.u[0] = bfp(f[0], f[1]); u.u[1] = bfp(f[2], f[3]);
      u.u[2] = bfp(f[4], f[5]); u.u[3] = bfp(f[6], f[7]);
      VF[((o >> 2) * 5 + 4) * 64 + (o & 3) * 16] = u.f;
    }
  }
  // ---- stage Q A-frags (scaled bf16) ----
#pragma unroll
  for (int it = 0; it < 4; ++it) {
    const int od = tid & 7, m = it * 32 + (tid >> 3);
    const float* src = q + (size_t)(b * LQ + q0 + m) * C + h * D + od * 8;
    float4 f0 = *(const float4*)src, f1 = *(const float4*)(src + 4);
    FragU u;
    u.u[0] = bfp(f0.x * SCALE, f0.y * SCALE);
    u.u[1] = bfp(f0.z * SCALE, f0.w * SCALE);
    u.u[2] = bfp(f1.x * SCALE, f1.y * SCALE);
    u.u[3] = bfp(f1.z * SCALE, f1.w * SCALE);
    QA[((m >> 4) * 2 + (od >> 2)) * 64 + (od & 3) * 16 + (m & 15)] = u.f;
  }
  // ---- stage codebook B-frags ----
  if (tid < 128) {
    const int od = tid & 7, j = tid >> 3;
    const float* src = cb + (size_t)j * C + h * D + od * 8;
    float4 f0 = *(const float4*)src, f1 = *(const float4*)(src + 4);
    FragU u;
    u.u[0] = bfp(f0.x, f0.y); u.u[1] = bfp(f0.z, f0.w);
    u.u[2] = bfp(f1.x, f1.y); u.u[3] = bfp(f1.z, f1.w);
    CBf[(od >> 2) * 64 + (od & 3) * 16 + j] = u.f;
  }
  __syncthreads();

  // ---- t = (scale q) . cb^T via MFMA (C layout: row=quad*4+r, col=j) ----
  f32x4 tacc[2];
#pragma unroll
  for (int mt2 = 0; mt2 < 2; ++mt2) {
    const int mt = wq * 2 + mt2;
    FragU a0, a1, b0, b1;
    a0.f = QA[(mt * 2 + 0) * 64 + lane];
    a1.f = QA[(mt * 2 + 1) * 64 + lane];
    b0.f = CBf[0 * 64 + lane];
    b1.f = CBf[1 * 64 + lane];
    f32x4 z = {0.f, 0.f, 0.f, 0.f};
    z = __builtin_amdgcn_mfma_f32_16x16x32_bf16(a0.s, b0.s, z, 0, 0, 0);
    z = __builtin_amdgcn_mfma_f32_16x16x32_bf16(a1.s, b1.s, z, 0, 0, 0);
    tacc[mt2] = z;
  }
  __syncthreads(); // all QA reads done -> TS alias safe

  // transpose t through LDS (per-wave private region; same-wave r/w ordering)
#pragma unroll
  for (int mt2 = 0; mt2 < 2; ++mt2) {
    const int mt = wq * 2 + mt2;
#pragma unroll
    for (int r = 0; r < 4; ++r)
      TS[mt * 272 + (quad * 4 + r) * 17 + (lane & 15)] = tacc[mt2][r];
  }
  float t0[16], t1[16];
#pragma unroll
  for (int j = 0; j < 16; ++j) {
    t0[j] = TS[(wq * 2 + 0) * 272 + (lane & 15) * 17 + j];
    t1[j] = TS[(wq * 2 + 1) * 272 + (lane & 15) * 17 + j];
  }

  // low-3-bit partial-sum tables
  float sl0[8], sl1[8];
#pragma unroll
  for (int c = 0; c < 8; ++c) {
    sl0[c] = ((c & 4) ? t0[5] : t0[13]) + ((c & 2) ? t0[6] : t0[14]) +
             ((c & 1) ? t0[7] : t0[15]);
    sl1[c] = ((c & 4) ? t1[5] : t1[13]) + ((c & 2) ? t1[6] : t1[14]) +
             ((c & 1) ? t1[7] : t1[15]);
  }

  f32x4 acc[2][5];
#pragma unroll
  for (int i = 0; i < 2; ++i)
#pragma unroll
    for (int t_ = 0; t_ < 5; ++t_) acc[i][t_] = (f32x4){0.f, 0.f, 0.f, 0.f};

  // ---- main loop: 8 K-chunks of 32 buckets ----
#pragma unroll
  for (int qc = 0; qc < 8; ++qc) {
    const int u = qc * 4 + quad; // k >> 3 for this lane's elements
    const float shi0 = ((u & 16) ? t0[0] : t0[8]) + ((u & 8) ? t0[1] : t0[9]) +
                       ((u & 4) ? t0[2] : t0[10]) + ((u & 2) ? t0[3] : t0[11]) +
                       ((u & 1) ? t0[4] : t0[12]);
    const float shi1 = ((u & 16) ? t1[0] : t1[8]) + ((u & 8) ? t1[1] : t1[9]) +
                       ((u & 4) ? t1[2] : t1[10]) + ((u & 2) ? t1[3] : t1[11]) +
                       ((u & 1) ? t1[4] : t1[12]);
    float p0[8], p1[8];
#pragma unroll
    for (int j = 0; j < 8; ++j) {
      p0[j] = __expf(shi0 + sl0[j]);
      p1[j] = __expf(shi1 + sl1[j]);
    }
    FragU a0, a1;
    a0.u[0] = bfp(p0[0], p0[1]); a0.u[1] = bfp(p0[2], p0[3]);
    a0.u[2] = bfp(p0[4], p0[5]); a0.u[3] = bfp(p0[6], p0[7]);
    a1.u[0] = bfp(p1[0], p1[1]); a1.u[1] = bfp(p1[2], p1[3]);
    a1.u[2] = bfp(p1[4], p1[5]); a1.u[3] = bfp(p1[6], p1[7]);
#pragma unroll
    for (int t_ = 0; t_ < 5; ++t_) {
      FragU bf_;
      bf_.f = VF[(qc * 5 + t_) * 64 + lane];
      acc[0][t_] = __builtin_amdgcn_mfma_f32_16x16x32_bf16(a0.s, bf_.s, acc[0][t_], 0, 0, 0);
      acc[1][t_] = __builtin_amdgcn_mfma_f32_16x16x32_bf16(a1.s, bf_.s, acc[1][t_], 0, 0, 0);
    }
  }

  // ---- epilogue: den broadcast from col-0 lane of each quad, divide, store
  const int srcl = lane & 48;
#pragma unroll
  for (int mt2 = 0; mt2 < 2; ++mt2) {
#pragma unroll
    for (int r = 0; r < 4; ++r) {
      const float den = __shfl(acc[mt2][4][r], srcl, 64);
      const float inv = 1.0f / den;
      const int row = q0 + wq * 32 + mt2 * 16 + quad * 4 + r;
      float* op = out + (size_t)(b * LQ + row) * C + h * D + (lane & 15);
#pragma unroll
      for (int t_ = 0; t_ < 4; ++t_) op[t_ * 16] = acc[mt2][t_][r] * inv;
    }
  }
}

// ---------------------------------------------------------------------------
extern "C" void kernel_launch(void* const* d_in, const int* in_sizes, int n_in,
                              void* d_out, int out_size, void* d_ws, size_t ws_size,
                              hipStream_t stream) {
  (void)in_sizes; (void)n_in; (void)out_size;
  const float* q  = (const float*)d_in[0];
  const float* k  = (const float*)d_in[1];
  const float* v  = (const float*)d_in[2];
  const float* Wc = (const float*)d_in[3];
  const float* bc = (const float*)d_in[4];
  const float* cb = (const float*)d_in[5];
  float* out = (float*)d_out;

  char* ws = (char*)d_ws;
  int*   idxp  = (int*)ws;                   // 128 KB
  float* cntp  = (float*)(ws + 0x20000);     // 8 KB
  float* codvp = (float*)(ws + 0x28000);     // 8 MB (final cod_v)
  const size_t need4 = 0x828000ull + 32ull * 1024 * 1024;
  const int R = (ws_size >= need4) ? 4 : 1;  // ws_size fixed -> deterministic
  float* parts = (R == 4) ? (float*)(ws + 0x828000) : codvp;

  hipMemsetAsync(cntp, 0, B * KC * sizeof(float), stream);
  hipLaunchKernelGGL(k_codes, dim3(1024), dim3(256), 0, stream,
                     k, Wc, bc, idxp, cntp);
  hipLaunchKernelGGL(k_scatter, dim3(C / 32, B, R), dim3(256), 0, stream,
                     v, idxp, parts, LK / R);
  if (R == 4)
    hipLaunchKernelGGL(k_merge, dim3(8192), dim3(256), 0, stream,
                       (const float4*)parts, (float4*)codvp);
  hipLaunchKernelGGL(k_attn, dim3(LQ / 128, H, B), dim3(256), 0, stream,
                     q, cb, codvp, cntp, out);
}

// Round 3
// 389.384 us; speedup vs baseline: 1.7203x; 1.3148x over previous
//
#include <hip/hip_runtime.h>
#include <hip/hip_bf16.h>

constexpr int B  = 8;
constexpr int LQ = 2048;
constexpr int LK = 4096;
constexpr int C  = 1024;
constexpr int H  = 16;
constexpr int D  = 64;
constexpr int CS = 8;
constexpr int KC = 256;
constexpr float SCALE = 0.125f;

typedef __attribute__((ext_vector_type(8))) short short8;
typedef __attribute__((ext_vector_type(4))) float f32x4;

union FragU { unsigned u[4]; short8 s; float4 f; };

__device__ inline unsigned bfp(float a, float b) {
  __hip_bfloat16 x = __float2bfloat16(a), y = __float2bfloat16(b);
  unsigned short ux = *reinterpret_cast<unsigned short*>(&x);
  unsigned short uy = *reinterpret_cast<unsigned short*>(&y);
  return (unsigned)ux | ((unsigned)uy << 16);
}

// ---------------------------------------------------------------------------
// Kernel 1: bucket index per kv token + per-(batch,bucket) counts (fp32 exact
// -- bf16 here would flip sign bits of near-zero codes and blow the absmax).
// ---------------------------------------------------------------------------
__global__ __launch_bounds__(256) void k_codes(
    const float* __restrict__ kmat, const float* __restrict__ Wc,
    const float* __restrict__ bc, int* __restrict__ idx,
    float* __restrict__ counts)
{
  __shared__ float wS[CS * C]; // 32 KB
  const int tid = threadIdx.x;
  {
    const float4* wsrc = (const float4*)Wc;
    float4* wdst = (float4*)wS;
#pragma unroll
    for (int i = 0; i < 8; ++i) wdst[tid + i * 256] = wsrc[tid + i * 256];
  }
  __syncthreads();

  const int wave = tid >> 6, lane = tid & 63;

  for (int i = 0; i < 8; ++i) {
    const int r = blockIdx.x * 32 + wave * 8 + i;
    const float4* krow = (const float4*)(kmat + (size_t)r * C);
    float acc[CS];
#pragma unroll
    for (int j = 0; j < CS; ++j) acc[j] = 0.f;
#pragma unroll
    for (int rep = 0; rep < 4; ++rep) {
      float4 kv = krow[rep * 64 + lane];
      const int dbase = (rep * 64 + lane) * 4;
#pragma unroll
      for (int j = 0; j < CS; ++j) {
        float4 wv = *(const float4*)&wS[j * C + dbase];
        acc[j] += kv.x * wv.x + kv.y * wv.y + kv.z * wv.z + kv.w * wv.w;
      }
    }
#pragma unroll
    for (int j = 0; j < CS; ++j) {
#pragma unroll
      for (int off = 32; off >= 1; off >>= 1)
        acc[j] += __shfl_xor(acc[j], off, 64);
    }
    if (lane == 0) {
      int ix = 0;
#pragma unroll
      for (int j = 0; j < CS; ++j) {
        float cj = acc[j] + bc[j];
        ix |= (cj >= 0.f ? 1 : 0) << (7 - j);
      }
      idx[r] = ix;
      const int bb = r >> 12; // r / LK
      atomicAdd(&counts[bb * KC + ix], 1.0f);
    }
  }
}

// ---------------------------------------------------------------------------
// Kernel 2a: exclusive prefix scan of counts -> global start offsets.
// One block; 8 batches x 256 buckets. Writes offs (for gather) and cursor
// (bumped by permute).
// ---------------------------------------------------------------------------
__global__ __launch_bounds__(256) void k_offsets(
    const float* __restrict__ counts, int* __restrict__ offs,
    int* __restrict__ cursor)
{
  __shared__ int s[KC];
  const int t = threadIdx.x;
  for (int b = 0; b < B; ++b) {
    int myc = (int)counts[b * KC + t];
    s[t] = myc;
    __syncthreads();
    // Hillis-Steele inclusive scan
#pragma unroll
    for (int off = 1; off < KC; off <<= 1) {
      int add = (t >= off) ? s[t - off] : 0;
      __syncthreads();
      s[t] += add;
      __syncthreads();
    }
    const int excl = s[t] - myc;
    offs[b * KC + t]   = b * LK + excl;
    cursor[b * KC + t] = b * LK + excl;
    __syncthreads();
  }
}

// ---------------------------------------------------------------------------
// Kernel 2b: build permutation: perm[offs[b][ix] ++] = row.
// ---------------------------------------------------------------------------
__global__ __launch_bounds__(256) void k_permute(
    const int* __restrict__ idx, int* __restrict__ cursor,
    int* __restrict__ perm)
{
  const int r = blockIdx.x * 256 + threadIdx.x; // < B*LK
  const int b = r >> 12;
  const int ix = idx[r];
  const int pos = atomicAdd(&cursor[b * KC + ix], 1);
  perm[pos] = r;
}

// ---------------------------------------------------------------------------
// Kernel 2c: gather-sum rows of each bucket. Block = (bucket, b); thread t
// owns columns [4t, 4t+4). Each iteration = one fully-coalesced 4 KB row.
// No atomics; register accumulation only.
// ---------------------------------------------------------------------------
__global__ __launch_bounds__(256) void k_gather(
    const float* __restrict__ v, const int* __restrict__ perm,
    const int* __restrict__ offs, const float* __restrict__ counts,
    float* __restrict__ cod_v)
{
  __shared__ int permS[512];
  const int t = threadIdx.x;
  const int ix = blockIdx.x, b = blockIdx.y;
  const int start = offs[b * KC + ix];
  const int cnt = (int)counts[b * KC + ix];

  float4 acc = make_float4(0.f, 0.f, 0.f, 0.f);
  for (int base = 0; base < cnt; base += 512) {
    const int n = min(512, cnt - base);
    __syncthreads();
    for (int i = t; i < n; i += 256) permS[i] = perm[start + base + i];
    __syncthreads();
    int i = 0;
    for (; i + 4 <= n; i += 4) {
      const int r0 = permS[i], r1 = permS[i + 1];
      const int r2 = permS[i + 2], r3 = permS[i + 3];
      float4 a = *(const float4*)(v + (size_t)r0 * C + t * 4);
      float4 b4 = *(const float4*)(v + (size_t)r1 * C + t * 4);
      float4 c4 = *(const float4*)(v + (size_t)r2 * C + t * 4);
      float4 d4 = *(const float4*)(v + (size_t)r3 * C + t * 4);
      acc.x += a.x + b4.x + c4.x + d4.x;
      acc.y += a.y + b4.y + c4.y + d4.y;
      acc.z += a.z + b4.z + c4.z + d4.z;
      acc.w += a.w + b4.w + c4.w + d4.w;
    }
    for (; i < n; ++i) {
      const int r0 = permS[i];
      float4 a = *(const float4*)(v + (size_t)r0 * C + t * 4);
      acc.x += a.x; acc.y += a.y; acc.z += a.z; acc.w += a.w;
    }
  }
  *(float4*)(cod_v + (size_t)(b * KC + ix) * C + t * 4) = acc;
}

// ---------------------------------------------------------------------------
// Kernel 3: attention via bf16 MFMA (unchanged from R2).
// ---------------------------------------------------------------------------
__global__ __launch_bounds__(256) void k_attn(
    const float* __restrict__ q, const float* __restrict__ cb,
    const float* __restrict__ cod_v, const float* __restrict__ counts,
    float* __restrict__ out)
{
  __shared__ __align__(16) char smem[59392];
  float4* VF = (float4*)smem;             // 2560 f4 : V B-frags (40960 B)
  float4* QA = (float4*)(smem + 40960);   // 1024 f4 : Q A-frags (16384 B)
  float4* CBf = (float4*)(smem + 57344);  // 128 f4  : cb B-frags (2048 B)
  float*  TS = (float*)(smem + 40960);    // alias over QA after barrier 2

  const int tid = threadIdx.x;
  const int lane = tid & 63, wq = tid >> 6, quad = lane >> 4;
  const int h = blockIdx.y, b = blockIdx.z;
  const int q0 = blockIdx.x * 128;

#pragma unroll
  for (int it = 0; it < 8; ++it) {
    const int o = it * 4 + (tid >> 6);
    const int n = tid & 63;
    const float* src = cod_v + (size_t)(b * KC + o * 8) * C + h * D + n;
    float f[8];
#pragma unroll
    for (int r = 0; r < 8; ++r) f[r] = src[(size_t)r * C];
    FragU u;
    u.u[0] = bfp(f[0], f[1]); u.u[1] = bfp(f[2], f[3]);
    u.u[2] = bfp(f[4], f[5]); u.u[3] = bfp(f[6], f[7]);
    VF[((o >> 2) * 5 + (n >> 4)) * 64 + (o & 3) * 16 + (n & 15)] = u.f;
  }
  {
    float4 z4 = make_float4(0.f, 0.f, 0.f, 0.f);
    for (int i = tid; i < 512; i += 256) {
      const int qc = i >> 6, l = i & 63;
      if ((l & 15) != 0) VF[(qc * 5 + 4) * 64 + l] = z4;
    }
    if (tid < 32) {
      const int o = tid;
      const float* cs = counts + b * KC + o * 8;
      float f[8];
#pragma unroll
      for (int r = 0; r < 8; ++r) f[r] = cs[r];
      FragU u;
      u.u[0] = bfp(f[0], f[1]); u.u[1] = bfp(f[2], f[3]);
      u.u[2] = bfp(f[4], f[5]); u.u[3] = bfp(f[6], f[7]);
      VF[((o >> 2) * 5 + 4) * 64 + (o & 3) * 16] = u.f;
    }
  }
#pragma unroll
  for (int it = 0; it < 4; ++it) {
    const int od = tid & 7, m = it * 32 + (tid >> 3);
    const float* src = q + (size_t)(b * LQ + q0 + m) * C + h * D + od * 8;
    float4 f0 = *(const float4*)src, f1 = *(const float4*)(src + 4);
    FragU u;
    u.u[0] = bfp(f0.x * SCALE, f0.y * SCALE);
    u.u[1] = bfp(f0.z * SCALE, f0.w * SCALE);
    u.u[2] = bfp(f1.x * SCALE, f1.y * SCALE);
    u.u[3] = bfp(f1.z * SCALE, f1.w * SCALE);
    QA[((m >> 4) * 2 + (od >> 2)) * 64 + (od & 3) * 16 + (m & 15)] = u.f;
  }
  if (tid < 128) {
    const int od = tid & 7, j = tid >> 3;
    const float* src = cb + (size_t)j * C + h * D + od * 8;
    float4 f0 = *(const float4*)src, f1 = *(const float4*)(src + 4);
    FragU u;
    u.u[0] = bfp(f0.x, f0.y); u.u[1] = bfp(f0.z, f0.w);
    u.u[2] = bfp(f1.x, f1.y); u.u[3] = bfp(f1.z, f1.w);
    CBf[(od >> 2) * 64 + (od & 3) * 16 + j] = u.f;
  }
  __syncthreads();

  f32x4 tacc[2];
#pragma unroll
  for (int mt2 = 0; mt2 < 2; ++mt2) {
    const int mt = wq * 2 + mt2;
    FragU a0, a1, b0, b1;
    a0.f = QA[(mt * 2 + 0) * 64 + lane];
    a1.f = QA[(mt * 2 + 1) * 64 + lane];
    b0.f = CBf[0 * 64 + lane];
    b1.f = CBf[1 * 64 + lane];
    f32x4 z = {0.f, 0.f, 0.f, 0.f};
    z = __builtin_amdgcn_mfma_f32_16x16x32_bf16(a0.s, b0.s, z, 0, 0, 0);
    z = __builtin_amdgcn_mfma_f32_16x16x32_bf16(a1.s, b1.s, z, 0, 0, 0);
    tacc[mt2] = z;
  }
  __syncthreads();

#pragma unroll
  for (int mt2 = 0; mt2 < 2; ++mt2) {
    const int mt = wq * 2 + mt2;
#pragma unroll
    for (int r = 0; r < 4; ++r)
      TS[mt * 272 + (quad * 4 + r) * 17 + (lane & 15)] = tacc[mt2][r];
  }
  float t0[16], t1[16];
#pragma unroll
  for (int j = 0; j < 16; ++j) {
    t0[j] = TS[(wq * 2 + 0) * 272 + (lane & 15) * 17 + j];
    t1[j] = TS[(wq * 2 + 1) * 272 + (lane & 15) * 17 + j];
  }

  float sl0[8], sl1[8];
#pragma unroll
  for (int c = 0; c < 8; ++c) {
    sl0[c] = ((c & 4) ? t0[5] : t0[13]) + ((c & 2) ? t0[6] : t0[14]) +
             ((c & 1) ? t0[7] : t0[15]);
    sl1[c] = ((c & 4) ? t1[5] : t1[13]) + ((c & 2) ? t1[6] : t1[14]) +
             ((c & 1) ? t1[7] : t1[15]);
  }

  f32x4 acc[2][5];
#pragma unroll
  for (int i = 0; i < 2; ++i)
#pragma unroll
    for (int t_ = 0; t_ < 5; ++t_) acc[i][t_] = (f32x4){0.f, 0.f, 0.f, 0.f};

#pragma unroll
  for (int qc = 0; qc < 8; ++qc) {
    const int u = qc * 4 + quad;
    const float shi0 = ((u & 16) ? t0[0] : t0[8]) + ((u & 8) ? t0[1] : t0[9]) +
                       ((u & 4) ? t0[2] : t0[10]) + ((u & 2) ? t0[3] : t0[11]) +
                       ((u & 1) ? t0[4] : t0[12]);
    const float shi1 = ((u & 16) ? t1[0] : t1[8]) + ((u & 8) ? t1[1] : t1[9]) +
                       ((u & 4) ? t1[2] : t1[10]) + ((u & 2) ? t1[3] : t1[11]) +
                       ((u & 1) ? t1[4] : t1[12]);
    float p0[8], p1[8];
#pragma unroll
    for (int j = 0; j < 8; ++j) {
      p0[j] = __expf(shi0 + sl0[j]);
      p1[j] = __expf(shi1 + sl1[j]);
    }
    FragU a0, a1;
    a0.u[0] = bfp(p0[0], p0[1]); a0.u[1] = bfp(p0[2], p0[3]);
    a0.u[2] = bfp(p0[4], p0[5]); a0.u[3] = bfp(p0[6], p0[7]);
    a1.u[0] = bfp(p1[0], p1[1]); a1.u[1] = bfp(p1[2], p1[3]);
    a1.u[2] = bfp(p1[4], p1[5]); a1.u[3] = bfp(p1[6], p1[7]);
#pragma unroll
    for (int t_ = 0; t_ < 5; ++t_) {
      FragU bf_;
      bf_.f = VF[(qc * 5 + t_) * 64 + lane];
      acc[0][t_] = __builtin_amdgcn_mfma_f32_16x16x32_bf16(a0.s, bf_.s, acc[0][t_], 0, 0, 0);
      acc[1][t_] = __builtin_amdgcn_mfma_f32_16x16x32_bf16(a1.s, bf_.s, acc[1][t_], 0, 0, 0);
    }
  }

  const int srcl = lane & 48;
#pragma unroll
  for (int mt2 = 0; mt2 < 2; ++mt2) {
#pragma unroll
    for (int r = 0; r < 4; ++r) {
      const float den = __shfl(acc[mt2][4][r], srcl, 64);
      const float inv = 1.0f / den;
      const int row = q0 + wq * 32 + mt2 * 16 + quad * 4 + r;
      float* op = out + (size_t)(b * LQ + row) * C + h * D + (lane & 15);
#pragma unroll
      for (int t_ = 0; t_ < 4; ++t_) op[t_ * 16] = acc[mt2][t_][r] * inv;
    }
  }
}

// ---------------------------------------------------------------------------
extern "C" void kernel_launch(void* const* d_in, const int* in_sizes, int n_in,
                              void* d_out, int out_size, void* d_ws, size_t ws_size,
                              hipStream_t stream) {
  (void)in_sizes; (void)n_in; (void)out_size; (void)ws_size;
  const float* q  = (const float*)d_in[0];
  const float* k  = (const float*)d_in[1];
  const float* v  = (const float*)d_in[2];
  const float* Wc = (const float*)d_in[3];
  const float* bc = (const float*)d_in[4];
  const float* cb = (const float*)d_in[5];
  float* out = (float*)d_out;

  char* ws = (char*)d_ws;
  int*   idxp  = (int*)ws;                    // 128 KB
  float* cntp  = (float*)(ws + 0x20000);      // 8 KB
  float* codvp = (float*)(ws + 0x28000);      // 8 MB
  int*   offsp = (int*)(ws + 0x828000);       // 8 KB
  int*   cursp = (int*)(ws + 0x82A000);       // 8 KB
  int*   permp = (int*)(ws + 0x82C000);       // 128 KB

  hipMemsetAsync(cntp, 0, B * KC * sizeof(float), stream);
  hipLaunchKernelGGL(k_codes, dim3(1024), dim3(256), 0, stream,
                     k, Wc, bc, idxp, cntp);
  hipLaunchKernelGGL(k_offsets, dim3(1), dim3(256), 0, stream,
                     cntp, offsp, cursp);
  hipLaunchKernelGGL(k_permute, dim3(B * LK / 256), dim3(256), 0, stream,
                     idxp, cursp, permp);
  hipLaunchKernelGGL(k_gather, dim3(KC, B), dim3(256), 0, stream,
                     v, permp, offsp, cntp, codvp);
  hipLaunchKernelGGL(k_attn, dim3(LQ / 128, H, B), dim3(256), 0, stream,
                     q, cb, codvp, cntp, out);
}

// Round 4
// 378.601 us; speedup vs baseline: 1.7693x; 1.0285x over previous
//
#include <hip/hip_runtime.h>
#include <hip/hip_bf16.h>

constexpr int B  = 8;
constexpr int LQ = 2048;
constexpr int LK = 4096;
constexpr int C  = 1024;
constexpr int H  = 16;
constexpr int D  = 64;
constexpr int CS = 8;
constexpr int KC = 256;
constexpr float SCALE = 0.125f;

typedef __attribute__((ext_vector_type(8))) short short8;
typedef __attribute__((ext_vector_type(4))) float f32x4;

union FragU { unsigned u[4]; short8 s; float4 f; };

__device__ inline unsigned bfp(float a, float b) {
  float2 f2; f2.x = a; f2.y = b;
  __hip_bfloat162 h = __float22bfloat162_rn(f2); // v_cvt_pk_bf16_f32
  return *reinterpret_cast<unsigned*>(&h);
}
__device__ inline unsigned short bf1(float a) {
  __hip_bfloat16 h = __float2bfloat16(a);
  return *reinterpret_cast<unsigned short*>(&h);
}

// ---------------------------------------------------------------------------
// Kernel 1: bucket index per kv token + per-(batch,bucket) counts (fp32 exact
// dot -- bf16 here could flip sign of near-zero codes).
// ---------------------------------------------------------------------------
__global__ __launch_bounds__(256) void k_codes(
    const float* __restrict__ kmat, const float* __restrict__ Wc,
    const float* __restrict__ bc, int* __restrict__ idx,
    float* __restrict__ counts)
{
  __shared__ float wS[CS * C]; // 32 KB
  const int tid = threadIdx.x;
  {
    const float4* wsrc = (const float4*)Wc;
    float4* wdst = (float4*)wS;
#pragma unroll
    for (int i = 0; i < 8; ++i) wdst[tid + i * 256] = wsrc[tid + i * 256];
  }
  __syncthreads();

  const int wave = tid >> 6, lane = tid & 63;

  for (int i = 0; i < 8; ++i) {
    const int r = blockIdx.x * 32 + wave * 8 + i;
    const float4* krow = (const float4*)(kmat + (size_t)r * C);
    float acc[CS];
#pragma unroll
    for (int j = 0; j < CS; ++j) acc[j] = 0.f;
#pragma unroll
    for (int rep = 0; rep < 4; ++rep) {
      float4 kv = krow[rep * 64 + lane];
      const int dbase = (rep * 64 + lane) * 4;
#pragma unroll
      for (int j = 0; j < CS; ++j) {
        float4 wv = *(const float4*)&wS[j * C + dbase];
        acc[j] += kv.x * wv.x + kv.y * wv.y + kv.z * wv.z + kv.w * wv.w;
      }
    }
#pragma unroll
    for (int j = 0; j < CS; ++j) {
#pragma unroll
      for (int off = 32; off >= 1; off >>= 1)
        acc[j] += __shfl_xor(acc[j], off, 64);
    }
    if (lane == 0) {
      int ix = 0;
#pragma unroll
      for (int j = 0; j < CS; ++j) {
        float cj = acc[j] + bc[j];
        ix |= (cj >= 0.f ? 1 : 0) << (7 - j);
      }
      idx[r] = ix;
      const int bb = r >> 12; // r / LK
      atomicAdd(&counts[bb * KC + ix], 1.0f);
    }
  }
}

// ---------------------------------------------------------------------------
// Kernel 2a: per-batch exclusive scan of counts (8 blocks, wave-shuffle scan)
// + build the bf16 counts-fragment tile (MFMA B-layout, n==0 col only).
// ---------------------------------------------------------------------------
__global__ __launch_bounds__(256) void k_offsets(
    const float* __restrict__ counts, int* __restrict__ offs,
    int* __restrict__ cursor, float4* __restrict__ vfc)
{
  __shared__ int wsum[4];
  const int b = blockIdx.x, t = threadIdx.x;
  const int lane = t & 63, w = t >> 6;
  const int myc = (int)counts[b * KC + t];
  int scan = myc;
#pragma unroll
  for (int off = 1; off < 64; off <<= 1) {
    int u = __shfl_up(scan, off, 64);
    if (lane >= off) scan += u;
  }
  if (lane == 63) wsum[w] = scan;
  __syncthreads();
  int base = 0;
#pragma unroll
  for (int i = 0; i < 4; ++i) base += (i < w) ? wsum[i] : 0;
  const int excl = base + scan - myc;
  offs[b * KC + t]   = b * LK + excl;
  cursor[b * KC + t] = b * LK + excl;

  for (int i = t; i < 512; i += 256) {
    const int qc = i >> 6, ln = i & 63;
    FragU u4;
    if ((ln & 15) == 0) {
      const int o = qc * 4 + (ln >> 4);
      const float* cs = counts + b * KC + o * 8;
      u4.u[0] = bfp(cs[0], cs[1]); u4.u[1] = bfp(cs[2], cs[3]);
      u4.u[2] = bfp(cs[4], cs[5]); u4.u[3] = bfp(cs[6], cs[7]);
    } else {
      u4.u[0] = u4.u[1] = u4.u[2] = u4.u[3] = 0u;
    }
    vfc[b * 512 + i] = u4.f;
  }
}

// ---------------------------------------------------------------------------
// Kernel 2b: build permutation: perm[cursor[b][ix]++] = row.
// ---------------------------------------------------------------------------
__global__ __launch_bounds__(256) void k_permute(
    const int* __restrict__ idx, int* __restrict__ cursor,
    int* __restrict__ perm)
{
  const int r = blockIdx.x * 256 + threadIdx.x;
  const int b = r >> 12;
  const int ix = idx[r];
  const int pos = atomicAdd(&cursor[b * KC + ix], 1);
  perm[pos] = r;
}

// ---------------------------------------------------------------------------
// Kernel 2c: gather-sum bucket rows; write result DIRECTLY as bf16 in MFMA
// B-fragment layout: vfb[(b*16+h)*2048 + slot]*8 ushorts, slot =
// ((o>>2)*4 + (n>>4))*64 + (o&3)*16 + (n&15), ushort r within; k = o*8+r.
// ---------------------------------------------------------------------------
__global__ __launch_bounds__(256) void k_gather(
    const float* __restrict__ v, const int* __restrict__ perm,
    const int* __restrict__ offs, const float* __restrict__ counts,
    unsigned short* __restrict__ vbf)
{
  __shared__ int permS[512];
  const int t = threadIdx.x;
  const int ix = blockIdx.x, b = blockIdx.y;
  const int start = offs[b * KC + ix];
  const int cnt = (int)counts[b * KC + ix];

  float4 acc = make_float4(0.f, 0.f, 0.f, 0.f);
  for (int base = 0; base < cnt; base += 512) {
    const int n = min(512, cnt - base);
    __syncthreads();
    for (int i = t; i < n; i += 256) permS[i] = perm[start + base + i];
    __syncthreads();
    int i = 0;
    for (; i + 4 <= n; i += 4) {
      const int r0 = permS[i], r1 = permS[i + 1];
      const int r2 = permS[i + 2], r3 = permS[i + 3];
      float4 a = *(const float4*)(v + (size_t)r0 * C + t * 4);
      float4 b4 = *(const float4*)(v + (size_t)r1 * C + t * 4);
      float4 c4 = *(const float4*)(v + (size_t)r2 * C + t * 4);
      float4 d4 = *(const float4*)(v + (size_t)r3 * C + t * 4);
      acc.x += a.x + b4.x + c4.x + d4.x;
      acc.y += a.y + b4.y + c4.y + d4.y;
      acc.z += a.z + b4.z + c4.z + d4.z;
      acc.w += a.w + b4.w + c4.w + d4.w;
    }
    for (; i < n; ++i) {
      const int r0 = permS[i];
      float4 a = *(const float4*)(v + (size_t)r0 * C + t * 4);
      acc.x += a.x; acc.y += a.y; acc.z += a.z; acc.w += a.w;
    }
  }

  const int h = t >> 4;              // global col = 4t; head = 4t/64
  const int n0 = (t & 15) * 4;       // col within head
  const int o = ix >> 3, r = ix & 7;
  const int slot0 = ((o >> 2) * 4 + (n0 >> 4)) * 64 + (o & 3) * 16 + (n0 & 15);
  unsigned short* dst = vbf + ((size_t)((b * 16 + h) * 2048 + slot0)) * 8 + r;
  dst[0]  = bf1(acc.x);
  dst[8]  = bf1(acc.y);
  dst[16] = bf1(acc.z);
  dst[24] = bf1(acc.w);
}

// ---------------------------------------------------------------------------
// Kernel 3: attention. V-frags read directly from global (L2-resident bf16
// frag image); LDS only for Q frags + codebook + t-transpose. exp factored:
// exp(shi+sl) = exp(shi)*exp(sl), esl precomputed (32 exps/lane vs 128).
// ---------------------------------------------------------------------------
__global__ __launch_bounds__(256) void k_attn(
    const float* __restrict__ q, const float* __restrict__ cb,
    const float4* __restrict__ vfb, const float4* __restrict__ vfc,
    float* __restrict__ out)
{
  __shared__ __align__(16) char smem[18432];
  float4* QA  = (float4*)smem;             // 1024 f4 (16384 B)
  float4* CBf = (float4*)(smem + 16384);   // 128 f4  (2048 B)
  float*  TS  = (float*)smem;              // alias over QA after t-MFMA

  const int tid = threadIdx.x;
  const int lane = tid & 63, wq = tid >> 6, quad = lane >> 4;
  const int h = blockIdx.y, b = blockIdx.z;
  const int q0 = blockIdx.x * 128;

  // ---- stage Q A-frags (scaled bf16) ----
#pragma unroll
  for (int it = 0; it < 4; ++it) {
    const int od = tid & 7, m = it * 32 + (tid >> 3);
    const float* src = q + (size_t)(b * LQ + q0 + m) * C + h * D + od * 8;
    float4 f0 = *(const float4*)src, f1 = *(const float4*)(src + 4);
    FragU u;
    u.u[0] = bfp(f0.x * SCALE, f0.y * SCALE);
    u.u[1] = bfp(f0.z * SCALE, f0.w * SCALE);
    u.u[2] = bfp(f1.x * SCALE, f1.y * SCALE);
    u.u[3] = bfp(f1.z * SCALE, f1.w * SCALE);
    QA[((m >> 4) * 2 + (od >> 2)) * 64 + (od & 3) * 16 + (m & 15)] = u.f;
  }
  // ---- stage codebook B-frags ----
  if (tid < 128) {
    const int od = tid & 7, j = tid >> 3;
    const float* src = cb + (size_t)j * C + h * D + od * 8;
    float4 f0 = *(const float4*)src, f1 = *(const float4*)(src + 4);
    FragU u;
    u.u[0] = bfp(f0.x, f0.y); u.u[1] = bfp(f0.z, f0.w);
    u.u[2] = bfp(f1.x, f1.y); u.u[3] = bfp(f1.z, f1.w);
    CBf[(od >> 2) * 64 + (od & 3) * 16 + j] = u.f;
  }
  __syncthreads();

  // ---- t = (scale q) . cb^T via MFMA ----
  f32x4 tacc[2];
#pragma unroll
  for (int mt2 = 0; mt2 < 2; ++mt2) {
    const int mt = wq * 2 + mt2;
    FragU a0, a1, b0, b1;
    a0.f = QA[(mt * 2 + 0) * 64 + lane];
    a1.f = QA[(mt * 2 + 1) * 64 + lane];
    b0.f = CBf[0 * 64 + lane];
    b1.f = CBf[1 * 64 + lane];
    f32x4 z = {0.f, 0.f, 0.f, 0.f};
    z = __builtin_amdgcn_mfma_f32_16x16x32_bf16(a0.s, b0.s, z, 0, 0, 0);
    z = __builtin_amdgcn_mfma_f32_16x16x32_bf16(a1.s, b1.s, z, 0, 0, 0);
    tacc[mt2] = z;
  }
  __syncthreads(); // QA reads done -> TS alias safe

  // transpose t through LDS (wave-private region)
#pragma unroll
  for (int mt2 = 0; mt2 < 2; ++mt2) {
    const int mt = wq * 2 + mt2;
#pragma unroll
    for (int r = 0; r < 4; ++r)
      TS[mt * 272 + (quad * 4 + r) * 17 + (lane & 15)] = tacc[mt2][r];
  }
  float t0[16], t1[16];
#pragma unroll
  for (int j = 0; j < 16; ++j) {
    t0[j] = TS[(wq * 2 + 0) * 272 + (lane & 15) * 17 + j];
    t1[j] = TS[(wq * 2 + 1) * 272 + (lane & 15) * 17 + j];
  }

  // exp of low-3-bit partial sums, precomputed
  float esl0[8], esl1[8];
#pragma unroll
  for (int c = 0; c < 8; ++c) {
    esl0[c] = __expf(((c & 4) ? t0[5] : t0[13]) + ((c & 2) ? t0[6] : t0[14]) +
                     ((c & 1) ? t0[7] : t0[15]));
    esl1[c] = __expf(((c & 4) ? t1[5] : t1[13]) + ((c & 2) ? t1[6] : t1[14]) +
                     ((c & 1) ? t1[7] : t1[15]));
  }

  f32x4 acc[2][5];
#pragma unroll
  for (int i = 0; i < 2; ++i)
#pragma unroll
    for (int t_ = 0; t_ < 5; ++t_) acc[i][t_] = (f32x4){0.f, 0.f, 0.f, 0.f};

  const float4* vb = vfb + (size_t)(b * 16 + h) * 2048 + lane;
  const float4* vc = vfc + b * 512 + lane;

  // ---- main loop: 8 K-chunks of 32 buckets ----
#pragma unroll
  for (int qc = 0; qc < 8; ++qc) {
    FragU bf0, bf1_, bf2, bf3, cf;
    bf0.f = vb[(qc * 4 + 0) * 64];
    bf1_.f = vb[(qc * 4 + 1) * 64];
    bf2.f = vb[(qc * 4 + 2) * 64];
    bf3.f = vb[(qc * 4 + 3) * 64];
    cf.f  = vc[qc * 64];

    const int u = qc * 4 + quad;
    const float eshi0 = __expf(
        ((u & 16) ? t0[0] : t0[8]) + ((u & 8) ? t0[1] : t0[9]) +
        ((u & 4) ? t0[2] : t0[10]) + ((u & 2) ? t0[3] : t0[11]) +
        ((u & 1) ? t0[4] : t0[12]));
    const float eshi1 = __expf(
        ((u & 16) ? t1[0] : t1[8]) + ((u & 8) ? t1[1] : t1[9]) +
        ((u & 4) ? t1[2] : t1[10]) + ((u & 2) ? t1[3] : t1[11]) +
        ((u & 1) ? t1[4] : t1[12]));

    FragU a0, a1;
    a0.u[0] = bfp(eshi0 * esl0[0], eshi0 * esl0[1]);
    a0.u[1] = bfp(eshi0 * esl0[2], eshi0 * esl0[3]);
    a0.u[2] = bfp(eshi0 * esl0[4], eshi0 * esl0[5]);
    a0.u[3] = bfp(eshi0 * esl0[6], eshi0 * esl0[7]);
    a1.u[0] = bfp(eshi1 * esl1[0], eshi1 * esl1[1]);
    a1.u[1] = bfp(eshi1 * esl1[2], eshi1 * esl1[3]);
    a1.u[2] = bfp(eshi1 * esl1[4], eshi1 * esl1[5]);
    a1.u[3] = bfp(eshi1 * esl1[6], eshi1 * esl1[7]);

    acc[0][0] = __builtin_amdgcn_mfma_f32_16x16x32_bf16(a0.s, bf0.s,  acc[0][0], 0, 0, 0);
    acc[1][0] = __builtin_amdgcn_mfma_f32_16x16x32_bf16(a1.s, bf0.s,  acc[1][0], 0, 0, 0);
    acc[0][1] = __builtin_amdgcn_mfma_f32_16x16x32_bf16(a0.s, bf1_.s, acc[0][1], 0, 0, 0);
    acc[1][1] = __builtin_amdgcn_mfma_f32_16x16x32_bf16(a1.s, bf1_.s, acc[1][1], 0, 0, 0);
    acc[0][2] = __builtin_amdgcn_mfma_f32_16x16x32_bf16(a0.s, bf2.s,  acc[0][2], 0, 0, 0);
    acc[1][2] = __builtin_amdgcn_mfma_f32_16x16x32_bf16(a1.s, bf2.s,  acc[1][2], 0, 0, 0);
    acc[0][3] = __builtin_amdgcn_mfma_f32_16x16x32_bf16(a0.s, bf3.s,  acc[0][3], 0, 0, 0);
    acc[1][3] = __builtin_amdgcn_mfma_f32_16x16x32_bf16(a1.s, bf3.s,  acc[1][3], 0, 0, 0);
    acc[0][4] = __builtin_amdgcn_mfma_f32_16x16x32_bf16(a0.s, cf.s,   acc[0][4], 0, 0, 0);
    acc[1][4] = __builtin_amdgcn_mfma_f32_16x16x32_bf16(a1.s, cf.s,   acc[1][4], 0, 0, 0);
  }

  // ---- epilogue ----
  const int srcl = lane & 48;
#pragma unroll
  for (int mt2 = 0; mt2 < 2; ++mt2) {
#pragma unroll
    for (int r = 0; r < 4; ++r) {
      const float den = __shfl(acc[mt2][4][r], srcl, 64);
      const float inv = 1.0f / den;
      const int row = q0 + wq * 32 + mt2 * 16 + quad * 4 + r;
      float* op = out + (size_t)(b * LQ + row) * C + h * D + (lane & 15);
#pragma unroll
      for (int t_ = 0; t_ < 4; ++t_) op[t_ * 16] = acc[mt2][t_][r] * inv;
    }
  }
}

// ---------------------------------------------------------------------------
extern "C" void kernel_launch(void* const* d_in, const int* in_sizes, int n_in,
                              void* d_out, int out_size, void* d_ws, size_t ws_size,
                              hipStream_t stream) {
  (void)in_sizes; (void)n_in; (void)out_size; (void)ws_size;
  const float* q  = (const float*)d_in[0];
  const float* k  = (const float*)d_in[1];
  const float* v  = (const float*)d_in[2];
  const float* Wc = (const float*)d_in[3];
  const float* bc = (const float*)d_in[4];
  const float* cb = (const float*)d_in[5];
  float* out = (float*)d_out;

  char* ws = (char*)d_ws;
  int*    idxp = (int*)ws;                         // 128 KB
  float*  cntp = (float*)(ws + 0x20000);           // 8 KB
  int*    offsp = (int*)(ws + 0x22000);            // 8 KB
  int*    cursp = (int*)(ws + 0x24000);            // 8 KB
  int*    permp = (int*)(ws + 0x26000);            // 128 KB
  float4* vfcp  = (float4*)(ws + 0x46000);         // 64 KB
  unsigned short* vbfp = (unsigned short*)(ws + 0x60000); // 4 MB

  hipMemsetAsync(cntp, 0, B * KC * sizeof(float), stream);
  hipLaunchKernelGGL(k_codes, dim3(1024), dim3(256), 0, stream,
                     k, Wc, bc, idxp, cntp);
  hipLaunchKernelGGL(k_offsets, dim3(B), dim3(256), 0, stream,
                     cntp, offsp, cursp, vfcp);
  hipLaunchKernelGGL(k_permute, dim3(B * LK / 256), dim3(256), 0, stream,
                     idxp, cursp, permp);
  hipLaunchKernelGGL(k_gather, dim3(KC, B), dim3(256), 0, stream,
                     v, permp, offsp, cntp, vbfp);
  hipLaunchKernelGGL(k_attn, dim3(LQ / 128, H, B), dim3(256), 0, stream,
                     q, cb, (const float4*)vbfp, (const float4*)vfcp, out);
}

// Round 5
// 375.161 us; speedup vs baseline: 1.7856x; 1.0092x over previous
//
#include <hip/hip_runtime.h>
#include <hip/hip_bf16.h>

constexpr int B  = 8;
constexpr int LQ = 2048;
constexpr int LK = 4096;
constexpr int C  = 1024;
constexpr int H  = 16;
constexpr int D  = 64;
constexpr int CS = 8;
constexpr int KC = 256;
constexpr float SCALE = 0.125f;

typedef __attribute__((ext_vector_type(8))) short short8;
typedef __attribute__((ext_vector_type(4))) float f32x4;

union FragU { unsigned u[4]; short8 s; float4 f; };

__device__ inline unsigned bfp(float a, float b) {
  float2 f2; f2.x = a; f2.y = b;
  __hip_bfloat162 h = __float22bfloat162_rn(f2); // v_cvt_pk_bf16_f32
  return *reinterpret_cast<unsigned*>(&h);
}
__device__ inline unsigned short bf1(float a) {
  __hip_bfloat16 h = __float2bfloat16(a);
  return *reinterpret_cast<unsigned short*>(&h);
}

// ---------------------------------------------------------------------------
// Kernel 1: bucket index per kv token (fp32-exact dot; bf16 would flip signs
// of near-zero codes and change bucket assignment vs the reference).
// No counts here -- k_sort rebuilds the histogram from idx.
// ---------------------------------------------------------------------------
__global__ __launch_bounds__(256) void k_codes(
    const float* __restrict__ kmat, const float* __restrict__ Wc,
    const float* __restrict__ bc, int* __restrict__ idx)
{
  __shared__ float wS[CS * C]; // 32 KB
  const int tid = threadIdx.x;
  {
    const float4* wsrc = (const float4*)Wc;
    float4* wdst = (float4*)wS;
#pragma unroll
    for (int i = 0; i < 8; ++i) wdst[tid + i * 256] = wsrc[tid + i * 256];
  }
  float bcr[CS];
#pragma unroll
  for (int j = 0; j < CS; ++j) bcr[j] = bc[j];
  __syncthreads();

  const int wave = tid >> 6, lane = tid & 63;

  for (int i = 0; i < 8; ++i) {
    const int r = blockIdx.x * 32 + wave * 8 + i;
    const float4* krow = (const float4*)(kmat + (size_t)r * C);
    float acc[CS];
#pragma unroll
    for (int j = 0; j < CS; ++j) acc[j] = 0.f;
#pragma unroll
    for (int rep = 0; rep < 4; ++rep) {
      float4 kv = krow[rep * 64 + lane];
      const int dbase = (rep * 64 + lane) * 4;
#pragma unroll
      for (int j = 0; j < CS; ++j) {
        float4 wv = *(const float4*)&wS[j * C + dbase];
        acc[j] += kv.x * wv.x + kv.y * wv.y + kv.z * wv.z + kv.w * wv.w;
      }
    }
#pragma unroll
    for (int j = 0; j < CS; ++j) {
#pragma unroll
      for (int off = 32; off >= 1; off >>= 1)
        acc[j] += __shfl_xor(acc[j], off, 64);
    }
    if (lane == 0) {
      int ix = 0;
#pragma unroll
      for (int j = 0; j < CS; ++j)
        ix |= ((acc[j] + bcr[j]) >= 0.f ? 1 : 0) << (7 - j);
      idx[r] = ix;
    }
  }
}

// ---------------------------------------------------------------------------
// Kernel 2 (fused): per-batch histogram + scan + permutation + counts tile.
// One block per batch; all cursor atomics in LDS. Replaces memset + offsets
// + permute (3 dispatches -> 1).
// ---------------------------------------------------------------------------
__global__ __launch_bounds__(256) void k_sort(
    const int* __restrict__ idx, int* __restrict__ offs,
    int* __restrict__ cnti, int* __restrict__ perm,
    float4* __restrict__ vfc)
{
  __shared__ int idxS[LK];  // 16 KB
  __shared__ int hist[KC];
  __shared__ int cur[KC];
  __shared__ int wsum[4];
  const int b = blockIdx.x, t = threadIdx.x;
  const int lane = t & 63, w = t >> 6;

  hist[t] = 0;
  __syncthreads();
  for (int i = t; i < LK; i += 256) {
    const int ix = idx[b * LK + i];
    idxS[i] = ix;
    atomicAdd(&hist[ix], 1);
  }
  __syncthreads();

  const int myc = hist[t];
  int scan = myc;
#pragma unroll
  for (int off = 1; off < 64; off <<= 1) {
    int u = __shfl_up(scan, off, 64);
    if (lane >= off) scan += u;
  }
  if (lane == 63) wsum[w] = scan;
  __syncthreads();
  int base = 0;
#pragma unroll
  for (int i = 0; i < 4; ++i) base += (i < w) ? wsum[i] : 0;
  const int start = b * LK + base + scan - myc;
  offs[b * KC + t] = start;
  cnti[b * KC + t] = myc;
  cur[t] = start;
  __syncthreads();

  // build permutation via LDS cursors
  for (int i = t; i < LK; i += 256) {
    const int pos = atomicAdd(&cur[idxS[i]], 1);
    perm[pos] = b * LK + i;
  }

  // counts fragment tile (MFMA B-layout, col 0 of each 16-col group)
  for (int i = t; i < 512; i += 256) {
    const int qc = i >> 6, ln = i & 63;
    FragU u4;
    if ((ln & 15) == 0) {
      const int* cs = hist + (qc * 4 + (ln >> 4)) * 8;
      u4.u[0] = bfp((float)cs[0], (float)cs[1]);
      u4.u[1] = bfp((float)cs[2], (float)cs[3]);
      u4.u[2] = bfp((float)cs[4], (float)cs[5]);
      u4.u[3] = bfp((float)cs[6], (float)cs[7]);
    } else {
      u4.u[0] = u4.u[1] = u4.u[2] = u4.u[3] = 0u;
    }
    vfc[b * 512 + i] = u4.f;
  }
}

// ---------------------------------------------------------------------------
// Kernel 3: gather-sum bucket rows; write bf16 MFMA B-fragment image.
// ---------------------------------------------------------------------------
__global__ __launch_bounds__(256) void k_gather(
    const float* __restrict__ v, const int* __restrict__ perm,
    const int* __restrict__ offs, const int* __restrict__ cnti,
    unsigned short* __restrict__ vbf)
{
  __shared__ int permS[512];
  const int t = threadIdx.x;
  const int ix = blockIdx.x, b = blockIdx.y;
  const int start = offs[b * KC + ix];
  const int cnt = cnti[b * KC + ix];

  float4 acc = make_float4(0.f, 0.f, 0.f, 0.f);
  for (int base = 0; base < cnt; base += 512) {
    const int n = min(512, cnt - base);
    __syncthreads();
    for (int i = t; i < n; i += 256) permS[i] = perm[start + base + i];
    __syncthreads();
    int i = 0;
    for (; i + 4 <= n; i += 4) {
      const int r0 = permS[i], r1 = permS[i + 1];
      const int r2 = permS[i + 2], r3 = permS[i + 3];
      float4 a = *(const float4*)(v + (size_t)r0 * C + t * 4);
      float4 b4 = *(const float4*)(v + (size_t)r1 * C + t * 4);
      float4 c4 = *(const float4*)(v + (size_t)r2 * C + t * 4);
      float4 d4 = *(const float4*)(v + (size_t)r3 * C + t * 4);
      acc.x += a.x + b4.x + c4.x + d4.x;
      acc.y += a.y + b4.y + c4.y + d4.y;
      acc.z += a.z + b4.z + c4.z + d4.z;
      acc.w += a.w + b4.w + c4.w + d4.w;
    }
    for (; i < n; ++i) {
      const int r0 = permS[i];
      float4 a = *(const float4*)(v + (size_t)r0 * C + t * 4);
      acc.x += a.x; acc.y += a.y; acc.z += a.z; acc.w += a.w;
    }
  }

  const int h = t >> 4;
  const int n0 = (t & 15) * 4;
  const int o = ix >> 3, r = ix & 7;
  const int slot0 = ((o >> 2) * 4 + (n0 >> 4)) * 64 + (o & 3) * 16 + (n0 & 15);
  unsigned short* dst = vbf + ((size_t)((b * 16 + h) * 2048 + slot0)) * 8 + r;
  dst[0]  = bf1(acc.x);
  dst[8]  = bf1(acc.y);
  dst[16] = bf1(acc.z);
  dst[24] = bf1(acc.w);
}

// ---------------------------------------------------------------------------
// Kernel 4: attention (unchanged from R4).
// ---------------------------------------------------------------------------
__global__ __launch_bounds__(256) void k_attn(
    const float* __restrict__ q, const float* __restrict__ cb,
    const float4* __restrict__ vfb, const float4* __restrict__ vfc,
    float* __restrict__ out)
{
  __shared__ __align__(16) char smem[18432];
  float4* QA  = (float4*)smem;             // 1024 f4 (16384 B)
  float4* CBf = (float4*)(smem + 16384);   // 128 f4  (2048 B)
  float*  TS  = (float*)smem;              // alias over QA after t-MFMA

  const int tid = threadIdx.x;
  const int lane = tid & 63, wq = tid >> 6, quad = lane >> 4;
  const int h = blockIdx.y, b = blockIdx.z;
  const int q0 = blockIdx.x * 128;

#pragma unroll
  for (int it = 0; it < 4; ++it) {
    const int od = tid & 7, m = it * 32 + (tid >> 3);
    const float* src = q + (size_t)(b * LQ + q0 + m) * C + h * D + od * 8;
    float4 f0 = *(const float4*)src, f1 = *(const float4*)(src + 4);
    FragU u;
    u.u[0] = bfp(f0.x * SCALE, f0.y * SCALE);
    u.u[1] = bfp(f0.z * SCALE, f0.w * SCALE);
    u.u[2] = bfp(f1.x * SCALE, f1.y * SCALE);
    u.u[3] = bfp(f1.z * SCALE, f1.w * SCALE);
    QA[((m >> 4) * 2 + (od >> 2)) * 64 + (od & 3) * 16 + (m & 15)] = u.f;
  }
  if (tid < 128) {
    const int od = tid & 7, j = tid >> 3;
    const float* src = cb + (size_t)j * C + h * D + od * 8;
    float4 f0 = *(const float4*)src, f1 = *(const float4*)(src + 4);
    FragU u;
    u.u[0] = bfp(f0.x, f0.y); u.u[1] = bfp(f0.z, f0.w);
    u.u[2] = bfp(f1.x, f1.y); u.u[3] = bfp(f1.z, f1.w);
    CBf[(od >> 2) * 64 + (od & 3) * 16 + j] = u.f;
  }
  __syncthreads();

  f32x4 tacc[2];
#pragma unroll
  for (int mt2 = 0; mt2 < 2; ++mt2) {
    const int mt = wq * 2 + mt2;
    FragU a0, a1, b0, b1;
    a0.f = QA[(mt * 2 + 0) * 64 + lane];
    a1.f = QA[(mt * 2 + 1) * 64 + lane];
    b0.f = CBf[0 * 64 + lane];
    b1.f = CBf[1 * 64 + lane];
    f32x4 z = {0.f, 0.f, 0.f, 0.f};
    z = __builtin_amdgcn_mfma_f32_16x16x32_bf16(a0.s, b0.s, z, 0, 0, 0);
    z = __builtin_amdgcn_mfma_f32_16x16x32_bf16(a1.s, b1.s, z, 0, 0, 0);
    tacc[mt2] = z;
  }
  __syncthreads();

#pragma unroll
  for (int mt2 = 0; mt2 < 2; ++mt2) {
    const int mt = wq * 2 + mt2;
#pragma unroll
    for (int r = 0; r < 4; ++r)
      TS[mt * 272 + (quad * 4 + r) * 17 + (lane & 15)] = tacc[mt2][r];
  }
  float t0[16], t1[16];
#pragma unroll
  for (int j = 0; j < 16; ++j) {
    t0[j] = TS[(wq * 2 + 0) * 272 + (lane & 15) * 17 + j];
    t1[j] = TS[(wq * 2 + 1) * 272 + (lane & 15) * 17 + j];
  }

  float esl0[8], esl1[8];
#pragma unroll
  for (int c = 0; c < 8; ++c) {
    esl0[c] = __expf(((c & 4) ? t0[5] : t0[13]) + ((c & 2) ? t0[6] : t0[14]) +
                     ((c & 1) ? t0[7] : t0[15]));
    esl1[c] = __expf(((c & 4) ? t1[5] : t1[13]) + ((c & 2) ? t1[6] : t1[14]) +
                     ((c & 1) ? t1[7] : t1[15]));
  }

  f32x4 acc[2][5];
#pragma unroll
  for (int i = 0; i < 2; ++i)
#pragma unroll
    for (int t_ = 0; t_ < 5; ++t_) acc[i][t_] = (f32x4){0.f, 0.f, 0.f, 0.f};

  const float4* vb = vfb + (size_t)(b * 16 + h) * 2048 + lane;
  const float4* vc = vfc + b * 512 + lane;

#pragma unroll
  for (int qc = 0; qc < 8; ++qc) {
    FragU bf0, bf1_, bf2, bf3, cf;
    bf0.f = vb[(qc * 4 + 0) * 64];
    bf1_.f = vb[(qc * 4 + 1) * 64];
    bf2.f = vb[(qc * 4 + 2) * 64];
    bf3.f = vb[(qc * 4 + 3) * 64];
    cf.f  = vc[qc * 64];

    const int u = qc * 4 + quad;
    const float eshi0 = __expf(
        ((u & 16) ? t0[0] : t0[8]) + ((u & 8) ? t0[1] : t0[9]) +
        ((u & 4) ? t0[2] : t0[10]) + ((u & 2) ? t0[3] : t0[11]) +
        ((u & 1) ? t0[4] : t0[12]));
    const float eshi1 = __expf(
        ((u & 16) ? t1[0] : t1[8]) + ((u & 8) ? t1[1] : t1[9]) +
        ((u & 4) ? t1[2] : t1[10]) + ((u & 2) ? t1[3] : t1[11]) +
        ((u & 1) ? t1[4] : t1[12]));

    FragU a0, a1;
    a0.u[0] = bfp(eshi0 * esl0[0], eshi0 * esl0[1]);
    a0.u[1] = bfp(eshi0 * esl0[2], eshi0 * esl0[3]);
    a0.u[2] = bfp(eshi0 * esl0[4], eshi0 * esl0[5]);
    a0.u[3] = bfp(eshi0 * esl0[6], eshi0 * esl0[7]);
    a1.u[0] = bfp(eshi1 * esl1[0], eshi1 * esl1[1]);
    a1.u[1] = bfp(eshi1 * esl1[2], eshi1 * esl1[3]);
    a1.u[2] = bfp(eshi1 * esl1[4], eshi1 * esl1[5]);
    a1.u[3] = bfp(eshi1 * esl1[6], eshi1 * esl1[7]);

    acc[0][0] = __builtin_amdgcn_mfma_f32_16x16x32_bf16(a0.s, bf0.s,  acc[0][0], 0, 0, 0);
    acc[1][0] = __builtin_amdgcn_mfma_f32_16x16x32_bf16(a1.s, bf0.s,  acc[1][0], 0, 0, 0);
    acc[0][1] = __builtin_amdgcn_mfma_f32_16x16x32_bf16(a0.s, bf1_.s, acc[0][1], 0, 0, 0);
    acc[1][1] = __builtin_amdgcn_mfma_f32_16x16x32_bf16(a1.s, bf1_.s, acc[1][1], 0, 0, 0);
    acc[0][2] = __builtin_amdgcn_mfma_f32_16x16x32_bf16(a0.s, bf2.s,  acc[0][2], 0, 0, 0);
    acc[1][2] = __builtin_amdgcn_mfma_f32_16x16x32_bf16(a1.s, bf2.s,  acc[1][2], 0, 0, 0);
    acc[0][3] = __builtin_amdgcn_mfma_f32_16x16x32_bf16(a0.s, bf3.s,  acc[0][3], 0, 0, 0);
    acc[1][3] = __builtin_amdgcn_mfma_f32_16x16x32_bf16(a1.s, bf3.s,  acc[1][3], 0, 0, 0);
    acc[0][4] = __builtin_amdgcn_mfma_f32_16x16x32_bf16(a0.s, cf.s,   acc[0][4], 0, 0, 0);
    acc[1][4] = __builtin_amdgcn_mfma_f32_16x16x32_bf16(a1.s, cf.s,   acc[1][4], 0, 0, 0);
  }

  const int srcl = lane & 48;
#pragma unroll
  for (int mt2 = 0; mt2 < 2; ++mt2) {
#pragma unroll
    for (int r = 0; r < 4; ++r) {
      const float den = __shfl(acc[mt2][4][r], srcl, 64);
      const float inv = 1.0f / den;
      const int row = q0 + wq * 32 + mt2 * 16 + quad * 4 + r;
      float* op = out + (size_t)(b * LQ + row) * C + h * D + (lane & 15);
#pragma unroll
      for (int t_ = 0; t_ < 4; ++t_) op[t_ * 16] = acc[mt2][t_][r] * inv;
    }
  }
}

// ---------------------------------------------------------------------------
extern "C" void kernel_launch(void* const* d_in, const int* in_sizes, int n_in,
                              void* d_out, int out_size, void* d_ws, size_t ws_size,
                              hipStream_t stream) {
  (void)in_sizes; (void)n_in; (void)out_size; (void)ws_size;
  const float* q  = (const float*)d_in[0];
  const float* k  = (const float*)d_in[1];
  const float* v  = (const float*)d_in[2];
  const float* Wc = (const float*)d_in[3];
  const float* bc = (const float*)d_in[4];
  const float* cb = (const float*)d_in[5];
  float* out = (float*)d_out;

  char* ws = (char*)d_ws;
  int*    idxp  = (int*)ws;                        // 128 KB
  int*    offsp = (int*)(ws + 0x20000);            // 8 KB
  int*    cntip = (int*)(ws + 0x22000);            // 8 KB
  int*    permp = (int*)(ws + 0x24000);            // 128 KB
  float4* vfcp  = (float4*)(ws + 0x44000);         // 64 KB
  unsigned short* vbfp = (unsigned short*)(ws + 0x60000); // 4 MB

  hipLaunchKernelGGL(k_codes, dim3(1024), dim3(256), 0, stream,
                     k, Wc, bc, idxp);
  hipLaunchKernelGGL(k_sort, dim3(B), dim3(256), 0, stream,
                     idxp, offsp, cntip, permp, vfcp);
  hipLaunchKernelGGL(k_gather, dim3(KC, B), dim3(256), 0, stream,
                     v, permp, offsp, cntip, vbfp);
  hipLaunchKernelGGL(k_attn, dim3(LQ / 128, H, B), dim3(256), 0, stream,
                     q, cb, (const float4*)vbfp, (const float4*)vfcp, out);
}